// Round 1
// 2865.165 us; speedup vs baseline: 1.2682x; 1.2682x over previous
//
#include <hip/hip_runtime.h>

// Problem constants
#define TOKENS 4096      // B*S
#define BATCH  16
#define SEQ    256
#define Hdim   768
#define FFdim  3072
#define NHEAD  12
#define NLBL   9
#define NLAYER 12
#define QKVS   2304      // fused q|k|v row stride

typedef unsigned short u16;
typedef __attribute__((ext_vector_type(8))) short short8;   // 8 bf16 (4 VGPRs) MFMA frag
typedef __attribute__((ext_vector_type(4))) float floatx4;  // MFMA acc

__device__ __forceinline__ float bf2f(u16 u) {
    union { unsigned int i; float f; } c; c.i = ((unsigned int)u) << 16; return c.f;
}
__device__ __forceinline__ u16 f2bf(float f) {
    union { float f; unsigned int i; } c; c.f = f;
    unsigned int u = c.i;
    u = u + 0x7fffu + ((u >> 16) & 1u);   // RNE
    return (u16)(u >> 16);
}

// async global->LDS, 16B per lane; LDS dest = wave-uniform base + lane*16
#define GLOAD16(gp, lp) __builtin_amdgcn_global_load_lds( \
    (__attribute__((address_space(1))) void*)(gp), \
    (__attribute__((address_space(3))) void*)(lp), 16, 0, 0)

// ---------------------------------------------------------------------------
// Per-layer weight convert+transpose: W (K x N) f32 row-major ->
// WT (N x K) bf16 row-major. Wq/Wk/Wv go into one concatenated (2304 x 768).
// 64x64 tiles via LDS; one launch covers all 6 matrices (1728 tiles).
// ---------------------------------------------------------------------------
__global__ __launch_bounds__(256) void k_conv_layer(
    const float* __restrict__ Wq, const float* __restrict__ Wk,
    const float* __restrict__ Wv, const float* __restrict__ Wo,
    const float* __restrict__ W1, const float* __restrict__ W2,
    u16* __restrict__ qkvT, u16* __restrict__ oT,
    u16* __restrict__ w1T, u16* __restrict__ w2T)
{
    int bid = blockIdx.x;
    const float* src; u16* dst; int K, N, t;
    if (bid < 576) {                 // Wq,Wk,Wv,Wo: 144 tiles each (12x12)
        int m = bid / 144; t = bid - m * 144;
        src = (m == 0) ? Wq : (m == 1) ? Wk : (m == 2) ? Wv : Wo;
        dst = (m < 3) ? (qkvT + (size_t)m * 768 * 768) : oT;
        K = 768; N = 768;
    } else if (bid < 1152) {         // W1: 768x3072 -> 12x48 tiles
        t = bid - 576; src = W1; dst = w1T; K = 768; N = 3072;
    } else {                         // W2: 3072x768 -> 48x12 tiles
        t = bid - 1152; src = W2; dst = w2T; K = 3072; N = 768;
    }
    int ntn = N >> 6;
    int tk = t / ntn, tn = t - tk * ntn;

    __shared__ float ld[64][65];
    int tid = threadIdx.x;
    int rr = tid >> 4;            // 0..15
    int cc = (tid & 15) * 4;      // 0..60
#pragma unroll
    for (int i = 0; i < 4; i++) {
        int k = tk * 64 + rr + i * 16;
        float4 v = *(const float4*)(src + (size_t)k * N + tn * 64 + cc);
        ld[rr + i * 16][cc + 0] = v.x;
        ld[rr + i * 16][cc + 1] = v.y;
        ld[rr + i * 16][cc + 2] = v.z;
        ld[rr + i * 16][cc + 3] = v.w;
    }
    __syncthreads();
    int n  = tid >> 2;            // 0..63
    int kc = (tid & 3) * 16;      // 0..48
    union { u16 h[16]; uint4 v[2]; } ob;
#pragma unroll
    for (int j = 0; j < 16; j++) ob.h[j] = f2bf(ld[kc + j][n]);
    u16* op = dst + (size_t)(tn * 64 + n) * K + tk * 64 + kc;
    *(uint4*)(op)     = ob.v[0];
    *(uint4*)(op + 8) = ob.v[1];
}

// concat q/k/v biases for all layers (once)
__global__ void k_biascat(const float* __restrict__ bq, const float* __restrict__ bk,
                          const float* __restrict__ bv, float* __restrict__ o)
{
    int l = blockIdx.x, t = threadIdx.x;
    o[l * QKVS + t]        = bq[l * Hdim + t];
    o[l * QKVS + 768 + t]  = bk[l * Hdim + t];
    o[l * QKVS + 1536 + t] = bv[l * Hdim + t];
}

// ---------------------------------------------------------------------------
// m97-structure GEMM: out = A(M x K) @ BT(N x K)^T + bias, both bf16.
// 128x128 tile, BK=32, linear LDS, global_load_lds width-16 staging.
// MODE 0: bf16 out; MODE 1: bf16 out + tanh-GELU; MODE 2: f32 out.
// ---------------------------------------------------------------------------
template<int MODE>
__global__ __launch_bounds__(256) void k_gemm(const u16* __restrict__ Ag, const u16* __restrict__ Bg,
                                              const float* __restrict__ bias, void* __restrict__ outp,
                                              int N, int K)
{
    __shared__ u16 As[128 * 32];
    __shared__ u16 Bs[128 * 32];
    const int tid  = threadIdx.x;
    const int lane = tid & 63, w = tid >> 6;
    const int wr = w >> 1, wc = w & 1;
    const int quad = lane >> 4, l16 = lane & 15;
    const int m0 = blockIdx.y * 128, n0 = blockIdx.x * 128;

    // staging: chunk c = i*256+tid covers row c>>2, cols ((c&3)*8..+7); 16B/lane
    const int r0 = tid >> 2, c0 = (tid & 3) * 8;
    const u16* a0 = Ag + (size_t)(m0 + r0) * K + c0;
    const u16* a1 = Ag + (size_t)(m0 + 64 + r0) * K + c0;
    const u16* b0 = Bg + (size_t)(n0 + r0) * K + c0;
    const u16* b1 = Bg + (size_t)(n0 + 64 + r0) * K + c0;
    u16* as0 = As + (size_t)(w * 64) * 8;
    u16* as1 = As + (size_t)(256 + w * 64) * 8;
    u16* bs0 = Bs + (size_t)(w * 64) * 8;
    u16* bs1 = Bs + (size_t)(256 + w * 64) * 8;

    const floatx4 vzero = {0.f, 0.f, 0.f, 0.f};
    floatx4 acc[4][4];
#pragma unroll
    for (int i = 0; i < 4; i++)
#pragma unroll
        for (int j = 0; j < 4; j++) acc[i][j] = vzero;

    for (int k0 = 0; k0 < K; k0 += 32) {
        GLOAD16(a0 + k0, as0);
        GLOAD16(a1 + k0, as1);
        GLOAD16(b0 + k0, bs0);
        GLOAD16(b1 + k0, bs1);
        __syncthreads();   // drains vmcnt -> staged tile visible
        short8 af[4], bfr[4];
#pragma unroll
        for (int mt = 0; mt < 4; mt++) af[mt]  = *(const short8*)(&As[(wr * 64 + mt * 16 + l16) * 32 + quad * 8]);
#pragma unroll
        for (int nt = 0; nt < 4; nt++) bfr[nt] = *(const short8*)(&Bs[(wc * 64 + nt * 16 + l16) * 32 + quad * 8]);
#pragma unroll
        for (int mt = 0; mt < 4; mt++)
#pragma unroll
            for (int nt = 0; nt < 4; nt++)
                acc[mt][nt] = __builtin_amdgcn_mfma_f32_16x16x32_bf16(af[mt], bfr[nt], acc[mt][nt], 0, 0, 0);
        __syncthreads();   // all waves done reading before next stage overwrites
    }
    // epilogue: C/D layout col=lane&15, row=quad*4+reg  [m89/m91 verified]
#pragma unroll
    for (int mt = 0; mt < 4; mt++) {
#pragma unroll
        for (int nt = 0; nt < 4; nt++) {
            int col = n0 + wc * 64 + nt * 16 + l16;
            float bv = bias[col];
#pragma unroll
            for (int r = 0; r < 4; r++) {
                int row = m0 + wr * 64 + mt * 16 + quad * 4 + r;
                float vv = acc[mt][nt][r] + bv;
                if (MODE == 1) {
                    float t = 0.7978845608028654f * (vv + 0.044715f * vv * vv * vv);
                    vv = 0.5f * vv * (1.0f + tanhf(t));
                }
                if (MODE == 2) ((float*)outp)[(size_t)row * N + col] = vv;
                else          ((u16*)outp)[(size_t)row * N + col] = f2bf(vv);
            }
        }
    }
}

// ---------------------------------------------------------------------------
// Embedding gather + LayerNorm. One block per token.
// ---------------------------------------------------------------------------
__global__ __launch_bounds__(256) void k_embed(const int* __restrict__ wid, const int* __restrict__ tidv,
                                               const float* __restrict__ we, const float* __restrict__ pe, const float* __restrict__ te,
                                               const float* __restrict__ g, const float* __restrict__ bb,
                                               float* __restrict__ xf, u16* __restrict__ xh)
{
    int i = blockIdx.x; int s = i & 255;
    int t = threadIdx.x;
    int wv = wid[i], tv = tidv[i];
    float e[3]; float sum = 0.f, sq = 0.f;
#pragma unroll
    for (int r = 0; r < 3; r++) {
        int j = t + r * 256;
        float x = we[(size_t)wv * Hdim + j] + pe[s * Hdim + j] + te[tv * Hdim + j];
        e[r] = x; sum += x; sq += x * x;
    }
    __shared__ float red[8];
    for (int off = 32; off; off >>= 1) { sum += __shfl_xor(sum, off); sq += __shfl_xor(sq, off); }
    if ((t & 63) == 0) { red[t >> 6] = sum; red[4 + (t >> 6)] = sq; }
    __syncthreads();
    sum = red[0] + red[1] + red[2] + red[3];
    sq  = red[4] + red[5] + red[6] + red[7];
    float mean = sum * (1.0f / Hdim);
    float var  = sq * (1.0f / Hdim) - mean * mean;
    float rstd = rsqrtf(var + 1e-12f);
#pragma unroll
    for (int r = 0; r < 3; r++) {
        int j = t + r * 256;
        float v = (e[r] - mean) * rstd * g[j] + bb[j];
        xf[(size_t)i * Hdim + j] = v;
        xh[(size_t)i * Hdim + j] = f2bf(v);
    }
}

// residual add + LayerNorm (f32), updates xf in place, writes bf16 mirror
__global__ __launch_bounds__(256) void k_addln(float* __restrict__ xf, const float* __restrict__ y,
                                               const float* __restrict__ g, const float* __restrict__ bb,
                                               u16* __restrict__ xh)
{
    int i = blockIdx.x; int t = threadIdx.x;
    float e[3]; float sum = 0.f, sq = 0.f;
#pragma unroll
    for (int r = 0; r < 3; r++) {
        int j = t + r * 256;
        float x = xf[(size_t)i * Hdim + j] + y[(size_t)i * Hdim + j];
        e[r] = x; sum += x; sq += x * x;
    }
    __shared__ float red[8];
    for (int off = 32; off; off >>= 1) { sum += __shfl_xor(sum, off); sq += __shfl_xor(sq, off); }
    if ((t & 63) == 0) { red[t >> 6] = sum; red[4 + (t >> 6)] = sq; }
    __syncthreads();
    sum = red[0] + red[1] + red[2] + red[3];
    sq  = red[4] + red[5] + red[6] + red[7];
    float mean = sum * (1.0f / Hdim);
    float var  = sq * (1.0f / Hdim) - mean * mean;
    float rstd = rsqrtf(var + 1e-12f);
#pragma unroll
    for (int r = 0; r < 3; r++) {
        int j = t + r * 256;
        float v = (e[r] - mean) * rstd * g[j] + bb[j];
        xf[(size_t)i * Hdim + j] = v;
        xh[(size_t)i * Hdim + j] = f2bf(v);
    }
}

// ---------------------------------------------------------------------------
// Fused MFMA attention on the fused QKV buffer (row stride 2304: q|k|v).
// One block per (b, head). 4 waves; wave w owns queries w*64..w*64+63.
// ---------------------------------------------------------------------------
__global__ __launch_bounds__(256, 2) void k_attn(const u16* __restrict__ qkv, const int* __restrict__ maskg,
                                                 u16* __restrict__ ctx)
{
    __shared__ u16 Vt[64 * 264];       // Vt[d][key], rows padded to 264 halves
    __shared__ u16 Ps[4 * 64 * 40];    // per-wave P chunk, rows padded to 40
    __shared__ float madd[256];
    int bh = blockIdx.x; int b = bh / NHEAD; int h = bh - b * NHEAD;
    int tid = threadIdx.x; int lane = tid & 63; int w = tid >> 6;
    int quad = lane >> 4, l16 = lane & 15;
    size_t baseq = (size_t)b * SEQ * QKVS + h * 64;       // q columns
    size_t basec = (size_t)b * SEQ * Hdim + h * 64;       // ctx out

    // stage V transposed (v = qkv columns 1536..2303)
#pragma unroll
    for (int i = 0; i < 8; i++) {
        int c = tid + i * 256; int key = c >> 3; int cc = (c & 7) << 3;
        uint4 vv = *(const uint4*)(qkv + baseq + 1536 + (size_t)key * QKVS + cc);
        const u16* p16 = (const u16*)&vv;
#pragma unroll
        for (int e = 0; e < 8; e++) Vt[(cc + e) * 264 + key] = p16[e];
    }
    madd[tid] = (1.0f - (float)maskg[b * SEQ + tid]) * -10000.0f;
    __syncthreads();

    // Q fragments in registers: A[m=lane&15][k=quad*8+j]
    short8 aq[4][2];
#pragma unroll
    for (int mt = 0; mt < 4; mt++)
#pragma unroll
        for (int kf = 0; kf < 2; kf++)
            aq[mt][kf] = *(const short8*)(qkv + baseq + (size_t)(w * 64 + mt * 16 + l16) * QKVS + kf * 32 + quad * 8);

    const floatx4 vzero = {0.f, 0.f, 0.f, 0.f};
    floatx4 acc[4][4];
    float l_run[4][4];
#pragma unroll
    for (int a = 0; a < 4; a++)
#pragma unroll
        for (int r = 0; r < 4; r++) { acc[a][r] = vzero; l_run[a][r] = 0.f; }

    u16* Pw = &Ps[w * 64 * 40];

    for (int kc = 0; kc < 8; kc++) {
        floatx4 sc[4][2];
#pragma unroll
        for (int mt = 0; mt < 4; mt++) { sc[mt][0] = vzero; sc[mt][1] = vzero; }
#pragma unroll
        for (int kf = 0; kf < 2; kf++) {
            short8 bk_[2];
#pragma unroll
            for (int nt = 0; nt < 2; nt++)
                bk_[nt] = *(const short8*)(qkv + baseq + 768 + (size_t)(kc * 32 + nt * 16 + l16) * QKVS + kf * 32 + quad * 8);
#pragma unroll
            for (int mt = 0; mt < 4; mt++)
#pragma unroll
                for (int nt = 0; nt < 2; nt++)
                    sc[mt][nt] = __builtin_amdgcn_mfma_f32_16x16x32_bf16(aq[mt][kf], bk_[nt], sc[mt][nt], 0, 0, 0);
        }
        float madd0 = madd[kc * 32 + l16];
        float madd1 = madd[kc * 32 + 16 + l16];
#pragma unroll
        for (int mt = 0; mt < 4; mt++) {
#pragma unroll
            for (int r = 0; r < 4; r++) {
                float p0 = __expf(sc[mt][0][r] * 0.125f + madd0);
                float p1 = __expf(sc[mt][1][r] * 0.125f + madd1);
                float ls = p0 + p1;
#pragma unroll
                for (int off = 1; off < 16; off <<= 1) ls += __shfl_xor(ls, off);
                l_run[mt][r] += ls;
                int row = mt * 16 + quad * 4 + r;
                Pw[row * 40 + l16]      = f2bf(p0);
                Pw[row * 40 + 16 + l16] = f2bf(p1);
            }
        }
        short8 ap[4], bv_[4];
#pragma unroll
        for (int nt = 0; nt < 4; nt++)
            bv_[nt] = *(const short8*)(&Vt[(nt * 16 + l16) * 264 + kc * 32 + quad * 8]);
#pragma unroll
        for (int mt = 0; mt < 4; mt++)
            ap[mt] = *(const short8*)(&Pw[(mt * 16 + l16) * 40 + quad * 8]);
#pragma unroll
        for (int mt = 0; mt < 4; mt++)
#pragma unroll
            for (int nt = 0; nt < 4; nt++)
                acc[mt][nt] = __builtin_amdgcn_mfma_f32_16x16x32_bf16(ap[mt], bv_[nt], acc[mt][nt], 0, 0, 0);
    }
#pragma unroll
    for (int mt = 0; mt < 4; mt++)
#pragma unroll
        for (int r = 0; r < 4; r++) {
            float inv = 1.0f / l_run[mt][r];
            int sq_ = w * 64 + mt * 16 + quad * 4 + r;
#pragma unroll
            for (int nt = 0; nt < 4; nt++)
                ctx[basec + (size_t)sq_ * Hdim + nt * 16 + l16] = f2bf(acc[mt][nt][r] * inv);
        }
}

// valid-token compaction indices (stable)
__global__ void k_compact(const int* __restrict__ vm, int* __restrict__ counts, int* __restrict__ srcidx)
{
    int b = blockIdx.x;
    if (threadIdx.x == 0) {
        int c = 0;
        for (int s = 0; s < SEQ; s++)
            if (vm[b * SEQ + s]) { srcidx[b * SEQ + c] = s; c++; }
        counts[b] = c;
    }
}

// classifier head: one wave per output row; rows >= counts[b] get softmax(cls_b)
__global__ __launch_bounds__(256) void k_cls(const u16* __restrict__ x, const int* __restrict__ counts,
                                             const int* __restrict__ srcidx, const float* __restrict__ Wc,
                                             const float* __restrict__ bc, float* __restrict__ out)
{
    int w = threadIdx.x >> 6, lane = threadIdx.x & 63;
    int row = blockIdx.x * 4 + w;
    int b = row >> 8, s = row & 255;
    float acc[NLBL];
#pragma unroll
    for (int n = 0; n < NLBL; n++) acc[n] = 0.f;
    int cnt = counts[b];
    if (s < cnt) {
        int src = srcidx[b * SEQ + s];
        const u16* xr = x + (size_t)(b * SEQ + src) * Hdim;
        for (int j = lane; j < Hdim; j += 64) {
            float xv = bf2f(xr[j]);
#pragma unroll
            for (int n = 0; n < NLBL; n++) acc[n] += xv * Wc[j * NLBL + n];
        }
    }
#pragma unroll
    for (int n = 0; n < NLBL; n++)
        for (int off = 32; off; off >>= 1) acc[n] += __shfl_xor(acc[n], off);
    if (lane == 0) {
        float lg[NLBL]; float mx = -1e30f;
#pragma unroll
        for (int n = 0; n < NLBL; n++) { lg[n] = acc[n] + bc[n]; mx = fmaxf(mx, lg[n]); }
        float se = 0.f;
#pragma unroll
        for (int n = 0; n < NLBL; n++) { lg[n] = __expf(lg[n] - mx); se += lg[n]; }
        float inv = 1.0f / se;
#pragma unroll
        for (int n = 0; n < NLBL; n++) out[(size_t)row * NLBL + n] = lg[n] * inv;
    }
}

extern "C" void kernel_launch(void* const* d_in, const int* in_sizes, int n_in,
                              void* d_out, int out_size, void* d_ws, size_t ws_size,
                              hipStream_t stream)
{
    (void)in_sizes; (void)n_in; (void)out_size; (void)ws_size;
    const int* word_ids = (const int*)d_in[0];
    const int* in_mask  = (const int*)d_in[1];
    const int* type_ids = (const int*)d_in[2];
    const int* valid    = (const int*)d_in[3];
    const float* word_emb = (const float*)d_in[4];
    const float* pos_emb  = (const float*)d_in[5];
    const float* type_emb = (const float*)d_in[6];
    const float* eg = (const float*)d_in[7];
    const float* eb = (const float*)d_in[8];
    const float* Wq = (const float*)d_in[9];  const float* bq = (const float*)d_in[10];
    const float* Wk = (const float*)d_in[11]; const float* bk = (const float*)d_in[12];
    const float* Wv = (const float*)d_in[13]; const float* bv = (const float*)d_in[14];
    const float* Wo = (const float*)d_in[15]; const float* bo = (const float*)d_in[16];
    const float* ag = (const float*)d_in[17]; const float* ab = (const float*)d_in[18];
    const float* W1 = (const float*)d_in[19]; const float* b1 = (const float*)d_in[20];
    const float* W2 = (const float*)d_in[21]; const float* b2 = (const float*)d_in[22];
    const float* fg = (const float*)d_in[23]; const float* fb = (const float*)d_in[24];
    const float* Wc = (const float*)d_in[25]; const float* bc = (const float*)d_in[26];
    float* out = (float*)d_out;

    // ---- workspace layout (~71 MiB; small arrays FIRST) ----
    char* p = (char*)d_ws;
    int* counts = (int*)p;
    int* srcidx = (int*)(p + 1024);
    p += 65536;
    float* x_f32 = (float*)p; p += (size_t)TOKENS * Hdim * 4;         // 12.6 MB
    u16* x_h  = (u16*)p; p += (size_t)TOKENS * Hdim * 2;              //  6.3 MB
    float* tmpf = (float*)p; p += (size_t)TOKENS * Hdim * 4;          // 12.6 MB
    u16* qkv_h = (u16*)p; p += (size_t)TOKENS * QKVS * 2;             // 18.9 MB
    u16* c_h  = (u16*)p; p += (size_t)TOKENS * Hdim * 2;              //  6.3 MB
    u16* h_h  = qkv_h;   // FFN hidden aliases qkv+c (TOKENS*FFdim exactly)
    // per-layer bf16 transposed weights (reused each layer)
    u16* wqkvT = (u16*)p; p += (size_t)QKVS * Hdim * 2;               //  3.5 MB
    u16* woT   = (u16*)p; p += (size_t)Hdim * Hdim * 2;               //  1.2 MB
    u16* w1T   = (u16*)p; p += (size_t)FFdim * Hdim * 2;              //  4.7 MB
    u16* w2T   = (u16*)p; p += (size_t)Hdim * FFdim * 2;              //  4.7 MB
    float* bqkv = (float*)p; p += (size_t)NLAYER * QKVS * 4;          //  0.1 MB

    k_embed<<<TOKENS, 256, 0, stream>>>(word_ids, type_ids, word_emb, pos_emb, type_emb, eg, eb, x_f32, x_h);
    k_compact<<<BATCH, 64, 0, stream>>>(valid, counts, srcidx);
    k_biascat<<<NLAYER, 768, 0, stream>>>(bq, bk, bv, bqkv);

    for (int l = 0; l < NLAYER; l++) {
        size_t HH = (size_t)Hdim * Hdim;
        size_t HF = (size_t)Hdim * FFdim;
        k_conv_layer<<<1728, 256, 0, stream>>>(Wq + l * HH, Wk + l * HH, Wv + l * HH, Wo + l * HH,
                                               W1 + l * HF, W2 + l * HF, wqkvT, woT, w1T, w2T);
        k_gemm<0><<<dim3(18, 32), 256, 0, stream>>>(x_h, wqkvT, bqkv + l * QKVS, qkv_h, QKVS, Hdim);
        k_attn<<<BATCH * NHEAD, 256, 0, stream>>>(qkv_h, in_mask, c_h);
        k_gemm<2><<<dim3(6, 32), 256, 0, stream>>>(c_h, woT, bo + l * Hdim, tmpf, Hdim, Hdim);
        k_addln<<<TOKENS, 256, 0, stream>>>(x_f32, tmpf, ag + l * Hdim, ab + l * Hdim, x_h);
        k_gemm<1><<<dim3(24, 32), 256, 0, stream>>>(x_h, w1T, b1 + l * FFdim, h_h, FFdim, Hdim);
        k_gemm<2><<<dim3(6, 32), 256, 0, stream>>>(h_h, w2T, b2 + l * Hdim, tmpf, Hdim, FFdim);
        k_addln<<<TOKENS, 256, 0, stream>>>(x_f32, tmpf, fg + l * Hdim, fb + l * Hdim, x_h);
    }
    k_cls<<<TOKENS / 4, 256, 0, stream>>>(x_h, counts, srcidx, Wc, bc, out);
}

// Round 2
// 2596.548 us; speedup vs baseline: 1.3994x; 1.1035x over previous
//
#include <hip/hip_runtime.h>

// Problem constants
#define TOKENS 4096      // B*S
#define BATCH  16
#define SEQ    256
#define Hdim   768
#define FFdim  3072
#define NHEAD  12
#define NLBL   9
#define NLAYER 12
#define QKVS   2304      // fused q|k|v row stride

typedef unsigned short u16;
typedef __attribute__((ext_vector_type(8))) short short8;   // 8 bf16 (4 VGPRs) MFMA frag
typedef __attribute__((ext_vector_type(4))) float floatx4;  // MFMA acc

__device__ __forceinline__ float bf2f(u16 u) {
    union { unsigned int i; float f; } c; c.i = ((unsigned int)u) << 16; return c.f;
}
__device__ __forceinline__ u16 f2bf(float f) {
    union { float f; unsigned int i; } c; c.f = f;
    unsigned int u = c.i;
    u = u + 0x7fffu + ((u >> 16) & 1u);   // RNE
    return (u16)(u >> 16);
}

// async global->LDS, 16B per lane; LDS dest = wave-uniform base + lane*16
#define GLOAD16(gp, lp) __builtin_amdgcn_global_load_lds( \
    (__attribute__((address_space(1))) void*)(gp), \
    (__attribute__((address_space(3))) void*)(lp), 16, 0, 0)

// ---------------------------------------------------------------------------
// Per-layer weight convert+transpose: W (K x N) f32 row-major ->
// WT (N x K) bf16 row-major. Wq/Wk/Wv go into one concatenated (2304 x 768).
// ---------------------------------------------------------------------------
__global__ __launch_bounds__(256) void k_conv_layer(
    const float* __restrict__ Wq, const float* __restrict__ Wk,
    const float* __restrict__ Wv, const float* __restrict__ Wo,
    const float* __restrict__ W1, const float* __restrict__ W2,
    u16* __restrict__ qkvT, u16* __restrict__ oT,
    u16* __restrict__ w1T, u16* __restrict__ w2T)
{
    int bid = blockIdx.x;
    const float* src; u16* dst; int K, N, t;
    if (bid < 576) {                 // Wq,Wk,Wv,Wo: 144 tiles each (12x12)
        int m = bid / 144; t = bid - m * 144;
        src = (m == 0) ? Wq : (m == 1) ? Wk : (m == 2) ? Wv : Wo;
        dst = (m < 3) ? (qkvT + (size_t)m * 768 * 768) : oT;
        K = 768; N = 768;
    } else if (bid < 1152) {         // W1: 768x3072 -> 12x48 tiles
        t = bid - 576; src = W1; dst = w1T; K = 768; N = 3072;
    } else {                         // W2: 3072x768 -> 48x12 tiles
        t = bid - 1152; src = W2; dst = w2T; K = 3072; N = 768;
    }
    int ntn = N >> 6;
    int tk = t / ntn, tn = t - tk * ntn;

    __shared__ float ld[64][65];
    int tid = threadIdx.x;
    int rr = tid >> 4;            // 0..15
    int cc = (tid & 15) * 4;      // 0..60
#pragma unroll
    for (int i = 0; i < 4; i++) {
        int k = tk * 64 + rr + i * 16;
        float4 v = *(const float4*)(src + (size_t)k * N + tn * 64 + cc);
        ld[rr + i * 16][cc + 0] = v.x;
        ld[rr + i * 16][cc + 1] = v.y;
        ld[rr + i * 16][cc + 2] = v.z;
        ld[rr + i * 16][cc + 3] = v.w;
    }
    __syncthreads();
    int n  = tid >> 2;            // 0..63
    int kc = (tid & 3) * 16;      // 0..48
    union { u16 h[16]; uint4 v[2]; } ob;
#pragma unroll
    for (int j = 0; j < 16; j++) ob.h[j] = f2bf(ld[kc + j][n]);
    u16* op = dst + (size_t)(tn * 64 + n) * K + tk * 64 + kc;
    *(uint4*)(op)     = ob.v[0];
    *(uint4*)(op + 8) = ob.v[1];
}

// concat q/k/v biases for all layers (once)
__global__ void k_biascat(const float* __restrict__ bq, const float* __restrict__ bk,
                          const float* __restrict__ bv, float* __restrict__ o)
{
    int l = blockIdx.x, t = threadIdx.x;
    o[l * QKVS + t]        = bq[l * Hdim + t];
    o[l * QKVS + 768 + t]  = bk[l * Hdim + t];
    o[l * QKVS + 1536 + t] = bv[l * Hdim + t];
}

// ---------------------------------------------------------------------------
// 2-phase prefetch GEMM: out = A(M x K) @ BT(N x K)^T + bias, both bf16.
// 128 x BN tile, BK=32, dbuf LDS, counted vmcnt across raw barriers (T3/T4
// minimum 2-phase). BN in {128, 64}.
// MODE 0: bf16 out; MODE 1: bf16 out + tanh-GELU; MODE 2: f32 out.
// ---------------------------------------------------------------------------
template<int MODE, int BN>
__global__ __launch_bounds__(256) void k_gemm(const u16* __restrict__ Ag, const u16* __restrict__ Bg,
                                              const float* __restrict__ bias, void* __restrict__ outp,
                                              int N, int K)
{
    constexpr int NFR = BN / 32;          // per-wave n-frags (wave covers BN/2)
    __shared__ u16 As[2][128 * 32];
    __shared__ u16 Bs[2][BN * 32];
    const int tid  = threadIdx.x;
    const int lane = tid & 63, w = tid >> 6;
    const int wr = w >> 1, wc = w & 1;
    const int quad = lane >> 4, l16 = lane & 15;
    const int m0 = blockIdx.y * 128, n0 = blockIdx.x * BN;

    // staging: chunk c = tid (+256) covers row c>>2, cols ((c&3)*8..+7); 16B/lane
    const int r0 = tid >> 2, c0 = (tid & 3) * 8;
    const u16* a0 = Ag + (size_t)(m0 + r0) * K + c0;
    const u16* a1 = a0 + (size_t)64 * K;
    const u16* b0 = Bg + (size_t)(n0 + r0) * K + c0;
    const u16* b1 = b0 + (size_t)64 * K;          // BN==128 only
    const int lofs0 = w * 512;                    // wave-uniform LDS chunk base (u16)
    const int lofs1 = 2048 + w * 512;

    const floatx4 vzero = {0.f, 0.f, 0.f, 0.f};
    floatx4 acc[4][NFR];
#pragma unroll
    for (int i = 0; i < 4; i++)
#pragma unroll
        for (int j = 0; j < NFR; j++) acc[i][j] = vzero;

    const int NT = K >> 5;

    // prologue: stage tile 0 into buf 0
    GLOAD16(a0, &As[0][lofs0]);
    GLOAD16(a1, &As[0][lofs1]);
    GLOAD16(b0, &Bs[0][lofs0]);
    if constexpr (BN == 128) GLOAD16(b1, &Bs[0][lofs1]);

    for (int t = 0; t < NT; t++) {
        const int cur = t & 1, nxt = cur ^ 1;
        if (t + 1 < NT) {
            const int k1 = (t + 1) << 5;
            GLOAD16(a0 + k1, &As[nxt][lofs0]);
            GLOAD16(a1 + k1, &As[nxt][lofs1]);
            GLOAD16(b0 + k1, &Bs[nxt][lofs0]);
            if constexpr (BN == 128) {
                GLOAD16(b1 + k1, &Bs[nxt][lofs1]);
                asm volatile("s_waitcnt vmcnt(4)" ::: "memory");   // drain current tile only
            } else {
                asm volatile("s_waitcnt vmcnt(3)" ::: "memory");
            }
        } else {
            asm volatile("s_waitcnt vmcnt(0)" ::: "memory");       // tail: drain last tile
        }
        __builtin_amdgcn_sched_barrier(0);
        __builtin_amdgcn_s_barrier();          // all waves: buf[cur] staged
        __builtin_amdgcn_sched_barrier(0);

        short8 af[4], bfr[NFR];
#pragma unroll
        for (int mt = 0; mt < 4; mt++)
            af[mt]  = *(const short8*)(&As[cur][(wr * 64 + mt * 16 + l16) * 32 + quad * 8]);
#pragma unroll
        for (int nt = 0; nt < NFR; nt++)
            bfr[nt] = *(const short8*)(&Bs[cur][(wc * (BN / 2) + nt * 16 + l16) * 32 + quad * 8]);
#pragma unroll
        for (int mt = 0; mt < 4; mt++)
#pragma unroll
            for (int nt = 0; nt < NFR; nt++)
                acc[mt][nt] = __builtin_amdgcn_mfma_f32_16x16x32_bf16(af[mt], bfr[nt], acc[mt][nt], 0, 0, 0);

        __builtin_amdgcn_sched_barrier(0);
        __builtin_amdgcn_s_barrier();          // all waves done reading buf[cur]
        __builtin_amdgcn_sched_barrier(0);     // pin: next STAGE may not hoist above
    }

    // epilogue: C/D layout col=lane&15, row=quad*4+reg  [m89/m91 verified]
#pragma unroll
    for (int mt = 0; mt < 4; mt++) {
#pragma unroll
        for (int nt = 0; nt < NFR; nt++) {
            int col = n0 + wc * (BN / 2) + nt * 16 + l16;
            float bv = bias[col];
#pragma unroll
            for (int r = 0; r < 4; r++) {
                int row = m0 + wr * 64 + mt * 16 + quad * 4 + r;
                float vv = acc[mt][nt][r] + bv;
                if (MODE == 1) {
                    float t = 0.7978845608028654f * (vv + 0.044715f * vv * vv * vv);
                    vv = 0.5f * vv * (1.0f + tanhf(t));
                }
                if (MODE == 2) ((float*)outp)[(size_t)row * N + col] = vv;
                else          ((u16*)outp)[(size_t)row * N + col] = f2bf(vv);
            }
        }
    }
}

// ---------------------------------------------------------------------------
// Embedding gather + LayerNorm. One block per token.
// ---------------------------------------------------------------------------
__global__ __launch_bounds__(256) void k_embed(const int* __restrict__ wid, const int* __restrict__ tidv,
                                               const float* __restrict__ we, const float* __restrict__ pe, const float* __restrict__ te,
                                               const float* __restrict__ g, const float* __restrict__ bb,
                                               float* __restrict__ xf, u16* __restrict__ xh)
{
    int i = blockIdx.x; int s = i & 255;
    int t = threadIdx.x;
    int wv = wid[i], tv = tidv[i];
    float e[3]; float sum = 0.f, sq = 0.f;
#pragma unroll
    for (int r = 0; r < 3; r++) {
        int j = t + r * 256;
        float x = we[(size_t)wv * Hdim + j] + pe[s * Hdim + j] + te[tv * Hdim + j];
        e[r] = x; sum += x; sq += x * x;
    }
    __shared__ float red[8];
    for (int off = 32; off; off >>= 1) { sum += __shfl_xor(sum, off); sq += __shfl_xor(sq, off); }
    if ((t & 63) == 0) { red[t >> 6] = sum; red[4 + (t >> 6)] = sq; }
    __syncthreads();
    sum = red[0] + red[1] + red[2] + red[3];
    sq  = red[4] + red[5] + red[6] + red[7];
    float mean = sum * (1.0f / Hdim);
    float var  = sq * (1.0f / Hdim) - mean * mean;
    float rstd = rsqrtf(var + 1e-12f);
#pragma unroll
    for (int r = 0; r < 3; r++) {
        int j = t + r * 256;
        float v = (e[r] - mean) * rstd * g[j] + bb[j];
        xf[(size_t)i * Hdim + j] = v;
        xh[(size_t)i * Hdim + j] = f2bf(v);
    }
}

// residual add + LayerNorm (f32), updates xf in place, writes bf16 mirror
__global__ __launch_bounds__(256) void k_addln(float* __restrict__ xf, const float* __restrict__ y,
                                               const float* __restrict__ g, const float* __restrict__ bb,
                                               u16* __restrict__ xh)
{
    int i = blockIdx.x; int t = threadIdx.x;
    float e[3]; float sum = 0.f, sq = 0.f;
#pragma unroll
    for (int r = 0; r < 3; r++) {
        int j = t + r * 256;
        float x = xf[(size_t)i * Hdim + j] + y[(size_t)i * Hdim + j];
        e[r] = x; sum += x; sq += x * x;
    }
    __shared__ float red[8];
    for (int off = 32; off; off >>= 1) { sum += __shfl_xor(sum, off); sq += __shfl_xor(sq, off); }
    if ((t & 63) == 0) { red[t >> 6] = sum; red[4 + (t >> 6)] = sq; }
    __syncthreads();
    sum = red[0] + red[1] + red[2] + red[3];
    sq  = red[4] + red[5] + red[6] + red[7];
    float mean = sum * (1.0f / Hdim);
    float var  = sq * (1.0f / Hdim) - mean * mean;
    float rstd = rsqrtf(var + 1e-12f);
#pragma unroll
    for (int r = 0; r < 3; r++) {
        int j = t + r * 256;
        float v = (e[r] - mean) * rstd * g[j] + bb[j];
        xf[(size_t)i * Hdim + j] = v;
        xh[(size_t)i * Hdim + j] = f2bf(v);
    }
}

// ---------------------------------------------------------------------------
// Fused MFMA attention on the fused QKV buffer (row stride 2304: q|k|v).
// One block per (b, head). 4 waves; wave w owns queries w*64..w*64+63.
// ---------------------------------------------------------------------------
__global__ __launch_bounds__(256, 2) void k_attn(const u16* __restrict__ qkv, const int* __restrict__ maskg,
                                                 u16* __restrict__ ctx)
{
    __shared__ u16 Vt[64 * 264];       // Vt[d][key], rows padded to 264 halves
    __shared__ u16 Ps[4 * 64 * 40];    // per-wave P chunk, rows padded to 40
    __shared__ float madd[256];
    int bh = blockIdx.x; int b = bh / NHEAD; int h = bh - b * NHEAD;
    int tid = threadIdx.x; int lane = tid & 63; int w = tid >> 6;
    int quad = lane >> 4, l16 = lane & 15;
    size_t baseq = (size_t)b * SEQ * QKVS + h * 64;       // q columns
    size_t basec = (size_t)b * SEQ * Hdim + h * 64;       // ctx out

    // stage V transposed (v = qkv columns 1536..2303)
#pragma unroll
    for (int i = 0; i < 8; i++) {
        int c = tid + i * 256; int key = c >> 3; int cc = (c & 7) << 3;
        uint4 vv = *(const uint4*)(qkv + baseq + 1536 + (size_t)key * QKVS + cc);
        const u16* p16 = (const u16*)&vv;
#pragma unroll
        for (int e = 0; e < 8; e++) Vt[(cc + e) * 264 + key] = p16[e];
    }
    madd[tid] = (1.0f - (float)maskg[b * SEQ + tid]) * -10000.0f;
    __syncthreads();

    // Q fragments in registers: A[m=lane&15][k=quad*8+j]
    short8 aq[4][2];
#pragma unroll
    for (int mt = 0; mt < 4; mt++)
#pragma unroll
        for (int kf = 0; kf < 2; kf++)
            aq[mt][kf] = *(const short8*)(qkv + baseq + (size_t)(w * 64 + mt * 16 + l16) * QKVS + kf * 32 + quad * 8);

    const floatx4 vzero = {0.f, 0.f, 0.f, 0.f};
    floatx4 acc[4][4];
    float l_run[4][4];
#pragma unroll
    for (int a = 0; a < 4; a++)
#pragma unroll
        for (int r = 0; r < 4; r++) { acc[a][r] = vzero; l_run[a][r] = 0.f; }

    u16* Pw = &Ps[w * 64 * 40];

    for (int kc = 0; kc < 8; kc++) {
        floatx4 sc[4][2];
#pragma unroll
        for (int mt = 0; mt < 4; mt++) { sc[mt][0] = vzero; sc[mt][1] = vzero; }
#pragma unroll
        for (int kf = 0; kf < 2; kf++) {
            short8 bk_[2];
#pragma unroll
            for (int nt = 0; nt < 2; nt++)
                bk_[nt] = *(const short8*)(qkv + baseq + 768 + (size_t)(kc * 32 + nt * 16 + l16) * QKVS + kf * 32 + quad * 8);
#pragma unroll
            for (int mt = 0; mt < 4; mt++)
#pragma unroll
                for (int nt = 0; nt < 2; nt++)
                    sc[mt][nt] = __builtin_amdgcn_mfma_f32_16x16x32_bf16(aq[mt][kf], bk_[nt], sc[mt][nt], 0, 0, 0);
        }
        float madd0 = madd[kc * 32 + l16];
        float madd1 = madd[kc * 32 + 16 + l16];
#pragma unroll
        for (int mt = 0; mt < 4; mt++) {
#pragma unroll
            for (int r = 0; r < 4; r++) {
                float p0 = __expf(sc[mt][0][r] * 0.125f + madd0);
                float p1 = __expf(sc[mt][1][r] * 0.125f + madd1);
                float ls = p0 + p1;
#pragma unroll
                for (int off = 1; off < 16; off <<= 1) ls += __shfl_xor(ls, off);
                l_run[mt][r] += ls;
                int row = mt * 16 + quad * 4 + r;
                Pw[row * 40 + l16]      = f2bf(p0);
                Pw[row * 40 + 16 + l16] = f2bf(p1);
            }
        }
        short8 ap[4], bv_[4];
#pragma unroll
        for (int nt = 0; nt < 4; nt++)
            bv_[nt] = *(const short8*)(&Vt[(nt * 16 + l16) * 264 + kc * 32 + quad * 8]);
#pragma unroll
        for (int mt = 0; mt < 4; mt++)
            ap[mt] = *(const short8*)(&Pw[(mt * 16 + l16) * 40 + quad * 8]);
#pragma unroll
        for (int mt = 0; mt < 4; mt++)
#pragma unroll
            for (int nt = 0; nt < 4; nt++)
                acc[mt][nt] = __builtin_amdgcn_mfma_f32_16x16x32_bf16(ap[mt], bv_[nt], acc[mt][nt], 0, 0, 0);
    }
#pragma unroll
    for (int mt = 0; mt < 4; mt++)
#pragma unroll
        for (int r = 0; r < 4; r++) {
            float inv = 1.0f / l_run[mt][r];
            int sq_ = w * 64 + mt * 16 + quad * 4 + r;
#pragma unroll
            for (int nt = 0; nt < 4; nt++)
                ctx[basec + (size_t)sq_ * Hdim + nt * 16 + l16] = f2bf(acc[mt][nt][r] * inv);
        }
}

// valid-token compaction indices (stable)
__global__ void k_compact(const int* __restrict__ vm, int* __restrict__ counts, int* __restrict__ srcidx)
{
    int b = blockIdx.x;
    if (threadIdx.x == 0) {
        int c = 0;
        for (int s = 0; s < SEQ; s++)
            if (vm[b * SEQ + s]) { srcidx[b * SEQ + c] = s; c++; }
        counts[b] = c;
    }
}

// classifier head: one wave per output row; rows >= counts[b] get softmax(cls_b)
__global__ __launch_bounds__(256) void k_cls(const u16* __restrict__ x, const int* __restrict__ counts,
                                             const int* __restrict__ srcidx, const float* __restrict__ Wc,
                                             const float* __restrict__ bc, float* __restrict__ out)
{
    int w = threadIdx.x >> 6, lane = threadIdx.x & 63;
    int row = blockIdx.x * 4 + w;
    int b = row >> 8, s = row & 255;
    float acc[NLBL];
#pragma unroll
    for (int n = 0; n < NLBL; n++) acc[n] = 0.f;
    int cnt = counts[b];
    if (s < cnt) {
        int src = srcidx[b * SEQ + s];
        const u16* xr = x + (size_t)(b * SEQ + src) * Hdim;
        for (int j = lane; j < Hdim; j += 64) {
            float xv = bf2f(xr[j]);
#pragma unroll
            for (int n = 0; n < NLBL; n++) acc[n] += xv * Wc[j * NLBL + n];
        }
    }
#pragma unroll
    for (int n = 0; n < NLBL; n++)
        for (int off = 32; off; off >>= 1) acc[n] += __shfl_xor(acc[n], off);
    if (lane == 0) {
        float lg[NLBL]; float mx = -1e30f;
#pragma unroll
        for (int n = 0; n < NLBL; n++) { lg[n] = acc[n] + bc[n]; mx = fmaxf(mx, lg[n]); }
        float se = 0.f;
#pragma unroll
        for (int n = 0; n < NLBL; n++) { lg[n] = __expf(lg[n] - mx); se += lg[n]; }
        float inv = 1.0f / se;
#pragma unroll
        for (int n = 0; n < NLBL; n++) out[(size_t)row * NLBL + n] = lg[n] * inv;
    }
}

extern "C" void kernel_launch(void* const* d_in, const int* in_sizes, int n_in,
                              void* d_out, int out_size, void* d_ws, size_t ws_size,
                              hipStream_t stream)
{
    (void)in_sizes; (void)n_in; (void)out_size; (void)ws_size;
    const int* word_ids = (const int*)d_in[0];
    const int* in_mask  = (const int*)d_in[1];
    const int* type_ids = (const int*)d_in[2];
    const int* valid    = (const int*)d_in[3];
    const float* word_emb = (const float*)d_in[4];
    const float* pos_emb  = (const float*)d_in[5];
    const float* type_emb = (const float*)d_in[6];
    const float* eg = (const float*)d_in[7];
    const float* eb = (const float*)d_in[8];
    const float* Wq = (const float*)d_in[9];  const float* bq = (const float*)d_in[10];
    const float* Wk = (const float*)d_in[11]; const float* bk = (const float*)d_in[12];
    const float* Wv = (const float*)d_in[13]; const float* bv = (const float*)d_in[14];
    const float* Wo = (const float*)d_in[15]; const float* bo = (const float*)d_in[16];
    const float* ag = (const float*)d_in[17]; const float* ab = (const float*)d_in[18];
    const float* W1 = (const float*)d_in[19]; const float* b1 = (const float*)d_in[20];
    const float* W2 = (const float*)d_in[21]; const float* b2 = (const float*)d_in[22];
    const float* fg = (const float*)d_in[23]; const float* fb = (const float*)d_in[24];
    const float* Wc = (const float*)d_in[25]; const float* bc = (const float*)d_in[26];
    float* out = (float*)d_out;

    // ---- workspace layout (~71 MiB; small arrays FIRST) ----
    char* p = (char*)d_ws;
    int* counts = (int*)p;
    int* srcidx = (int*)(p + 1024);
    p += 65536;
    float* x_f32 = (float*)p; p += (size_t)TOKENS * Hdim * 4;         // 12.6 MB
    u16* x_h  = (u16*)p; p += (size_t)TOKENS * Hdim * 2;              //  6.3 MB
    float* tmpf = (float*)p; p += (size_t)TOKENS * Hdim * 4;          // 12.6 MB
    u16* qkv_h = (u16*)p; p += (size_t)TOKENS * QKVS * 2;             // 18.9 MB
    u16* c_h  = (u16*)p; p += (size_t)TOKENS * Hdim * 2;              //  6.3 MB
    u16* h_h  = qkv_h;   // FFN hidden aliases qkv+c (TOKENS*FFdim exactly)
    // per-layer bf16 transposed weights (reused each layer)
    u16* wqkvT = (u16*)p; p += (size_t)QKVS * Hdim * 2;               //  3.5 MB
    u16* woT   = (u16*)p; p += (size_t)Hdim * Hdim * 2;               //  1.2 MB
    u16* w1T   = (u16*)p; p += (size_t)FFdim * Hdim * 2;              //  4.7 MB
    u16* w2T   = (u16*)p; p += (size_t)Hdim * FFdim * 2;              //  4.7 MB
    float* bqkv = (float*)p; p += (size_t)NLAYER * QKVS * 4;          //  0.1 MB

    k_embed<<<TOKENS, 256, 0, stream>>>(word_ids, type_ids, word_emb, pos_emb, type_emb, eg, eb, x_f32, x_h);
    k_compact<<<BATCH, 64, 0, stream>>>(valid, counts, srcidx);
    k_biascat<<<NLAYER, 768, 0, stream>>>(bq, bk, bv, bqkv);

    for (int l = 0; l < NLAYER; l++) {
        size_t HH = (size_t)Hdim * Hdim;
        size_t HF = (size_t)Hdim * FFdim;
        k_conv_layer<<<1728, 256, 0, stream>>>(Wq + l * HH, Wk + l * HH, Wv + l * HH, Wo + l * HH,
                                               W1 + l * HF, W2 + l * HF, wqkvT, woT, w1T, w2T);
        k_gemm<0, 128><<<dim3(18, 32), 256, 0, stream>>>(x_h, wqkvT, bqkv + l * QKVS, qkv_h, QKVS, Hdim);
        k_attn<<<BATCH * NHEAD, 256, 0, stream>>>(qkv_h, in_mask, c_h);
        k_gemm<2, 64><<<dim3(12, 32), 256, 0, stream>>>(c_h, woT, bo + l * Hdim, tmpf, Hdim, Hdim);
        k_addln<<<TOKENS, 256, 0, stream>>>(x_f32, tmpf, ag + l * Hdim, ab + l * Hdim, x_h);
        k_gemm<1, 128><<<dim3(24, 32), 256, 0, stream>>>(x_h, w1T, b1 + l * FFdim, h_h, FFdim, Hdim);
        k_gemm<2, 64><<<dim3(12, 32), 256, 0, stream>>>(h_h, w2T, b2 + l * Hdim, tmpf, Hdim, FFdim);
        k_addln<<<TOKENS, 256, 0, stream>>>(x_f32, tmpf, fg + l * Hdim, fb + l * Hdim, x_h);
    }
    k_cls<<<TOKENS / 4, 256, 0, stream>>>(x_h, counts, srcidx, Wc, bc, out);
}